// Round 13
// baseline (81.274 us; speedup 1.0000x reference)
//
#include <hip/hip_runtime.h>

#define N_NODES 50000
#define N_EDGES 800000
#define DF      96
#define HID     256
#define OUTF    40
#define BM      64
#define NPART   512
#define CS      32     // cell capacity (mean 4; 128B-aligned; overflow ~1e-15)
#define PCAP2   2048   // per-partition LDS sorted capacity (mean ~1563)

#define EPB     2048                                // edges per bin block
#define NBE     ((N_EDGES + EPB - 1) / EPB)         // 391 bin blocks

#define FEAT_THREADS (N_NODES * DF / 8)             // 600000
#define FEAT_BLKS ((FEAT_THREADS + 255) / 256)      // 2344
#define WSHUF_ELEMS ((96 + 128 + 24) * 512)         // 126976
#define WSHUF_BLKS (WSHUF_ELEMS / 256)              // 496

typedef __attribute__((ext_vector_type(8))) short bf16x8;
typedef __attribute__((ext_vector_type(4))) float f32x4;

static __device__ __forceinline__ unsigned short f2bf(float f) {
    unsigned int u = __float_as_uint(f);
    u += 0x7fffu + ((u >> 16) & 1u);
    return (unsigned short)(u >> 16);
}
static __device__ __forceinline__ int part_of(int d) {
    return (int)(((long long)d * NPART) / N_NODES);
}
static __device__ __forceinline__ int part_n0(int p) {
    return (int)(((long long)p * N_NODES + NPART - 1) / NPART);
}

// ---------------------------------------------------------------------------
// K1: feat f32->bf16 | weight pre-shuffle | cell-based edge binning (NPART=512)
// (byte-identical to round 12)
// ---------------------------------------------------------------------------
__global__ __launch_bounds__(256) void k1_prep_bin(
    const float* __restrict__ feat, const float* __restrict__ W1,
    const float* __restrict__ W2, const float* __restrict__ W3,
    const int* __restrict__ src, const int* __restrict__ dst,
    uint4* __restrict__ featbf, unsigned short* __restrict__ W1s,
    unsigned short* __restrict__ W2s, unsigned short* __restrict__ W3s,
    unsigned int* __restrict__ packed2, int* __restrict__ cellCnt)
{
    const int bid = blockIdx.x, t = threadIdx.x;
    if (bid < FEAT_BLKS) {
        int i = bid * 256 + t;                     // 8 floats per thread
        if (i < FEAT_THREADS) {
            const float4* p = reinterpret_cast<const float4*>(feat) + (size_t)i * 2;
            float4 v0 = p[0], v1 = p[1];
            uint4 pk;
            pk.x = (unsigned)f2bf(v0.x) | ((unsigned)f2bf(v0.y) << 16);
            pk.y = (unsigned)f2bf(v0.z) | ((unsigned)f2bf(v0.w) << 16);
            pk.z = (unsigned)f2bf(v1.x) | ((unsigned)f2bf(v1.y) << 16);
            pk.w = (unsigned)f2bf(v1.z) | ((unsigned)f2bf(v1.w) << 16);
            featbf[i] = pk;
        }
        return;
    }
    if (bid < FEAT_BLKS + WSHUF_BLKS) {
        int i = (bid - FEAT_BLKS) * 256 + t;       // < WSHUF_ELEMS exactly
        int j  = i & 7;
        int l  = (i >> 3) & 63;
        int fi = i >> 9;
        int kg = l >> 4, n16 = l & 15;
        if (fi < 96) {
            int tt = fi / 6, s = fi % 6;
            int k = s * 32 + kg * 8 + j, n = tt * 16 + n16;
            W1s[i] = f2bf(W1[(size_t)k * HID + n]);
        } else if (fi < 96 + 128) {
            int f2 = fi - 96;
            int tt = f2 / 8, s = f2 % 8;
            int k = s * 32 + kg * 8 + j, n = tt * 16 + n16;
            W2s[i - 96 * 512] = f2bf(W2[(size_t)k * HID + n]);
        } else {
            int f3 = fi - 224;
            int tt = f3 / 8, s = f3 % 8;
            int k = s * 32 + kg * 8 + j, n = tt * 16 + n16;
            W3s[i - 224 * 512] = (n < OUTF) ? f2bf(W3[(size_t)k * OUTF + n])
                                            : (unsigned short)0;
        }
        return;
    }
    // ---- edge binning ----
    {
        __shared__ int cur[NPART];
        const int bid2 = bid - FEAT_BLKS - WSHUF_BLKS;   // < NBE
        cur[t] = 0;
        cur[t + 256] = 0;
        __syncthreads();
        int pv[8], pos[8];
        unsigned pkv[8];
        bool valid[8];
#pragma unroll
        for (int k = 0; k < 8; ++k) {
            int e = bid2 * EPB + k * 256 + t;
            valid[k] = (e < N_EDGES);
            pv[k] = 0; pkv[k] = 0; pos[k] = CS;
            if (valid[k]) {
                int d = dst[e], s = src[e];
                int p = part_of(d);
                pv[k] = p;
                pkv[k] = ((unsigned)(d - part_n0(p)) << 16) | (unsigned)s;
                pos[k] = atomicAdd(&cur[p], 1);
            }
        }
        __syncthreads();
#pragma unroll
        for (int q = 0; q < 2; ++q) {
            int pp = q * 256 + t;
            cellCnt[(size_t)pp * NBE + bid2] = (cur[pp] < CS) ? cur[pp] : CS;
        }
#pragma unroll
        for (int k = 0; k < 8; ++k) {
            if (valid[k] && pos[k] < CS)
                packed2[((size_t)pv[k] * NBE + bid2) * CS + pos[k]] = pkv[k];
        }
    }
}

// ---------------------------------------------------------------------------
// part_agg: per-partition in-LDS counting sort + neighbor-mean aggregation.
// Sort phases unchanged from round 12. Gather changed: each wave processes
// FOUR nodes concurrently at depth-4 (16 rows in flight vs 8) to raise
// memory-level parallelism on the L3-served random gather.
// ---------------------------------------------------------------------------
__global__ __launch_bounds__(1024, 4) void part_agg(
    const unsigned int* __restrict__ packed2, const int* __restrict__ cellCnt,
    const unsigned int* __restrict__ featbf, unsigned int* __restrict__ nbr32)
{
    __shared__ int hist[128];
    __shared__ int scanex[128];
    __shared__ int cur[128];
    __shared__ int nodeOff[128];
    __shared__ int nodeCnt[128];
    __shared__ unsigned short srcLDS[PCAP2];
    const int p = blockIdx.x, t = threadIdx.x;
    const int n0 = part_n0(p);
    const int nl = part_n0(p + 1) - n0;              // <= 98
    const unsigned int* cells = packed2 + (size_t)p * NBE * CS;
    const int* ccnt = cellCnt + (size_t)p * NBE;

    if (t < 128) hist[t] = 0;
    __syncthreads();
    // pass 1: histogram of dst_local over cell prefixes
    for (int c = t; c < NBE; c += 1024) {
        int cnt = ccnt[c];
        const unsigned int* cp = cells + (size_t)c * CS;
        for (int i = 0; i < cnt; ++i)
            atomicAdd(&hist[cp[i] >> 16], 1);
    }
    __syncthreads();
    int v = 0;
    if (t < 128) { v = hist[t]; scanex[t] = v; }
    __syncthreads();
    for (int off = 1; off < 128; off <<= 1) {
        int x = 0;
        if (t < 128 && t >= off) x = scanex[t - off];
        __syncthreads();
        if (t < 128) scanex[t] += x;
        __syncthreads();
    }
    if (t < 128) {
        int ex = scanex[t] - v;
        cur[t] = ex;
        nodeOff[t] = ex;
        nodeCnt[t] = v;
    }
    __syncthreads();
    // pass 2: rank into LDS
    for (int c = t; c < NBE; c += 1024) {
        int cnt = ccnt[c];
        const unsigned int* cp = cells + (size_t)c * CS;
        for (int i = 0; i < cnt; ++i) {
            unsigned pk = cp[i];
            int r = atomicAdd(&cur[pk >> 16], 1);
            if (r < PCAP2) srcLDS[r] = (unsigned short)(pk & 0xffffu);
        }
    }
    __syncthreads();
    // gather: wave handles nodes n0g..n0g+3 concurrently, depth-4 batches
    const int wv = t >> 6, lane = t & 63;
    const bool act = (lane < 48);
    for (int n0g = 4 * wv; n0g < nl; n0g += 64) {
        int begv[4], cntv[4];
#pragma unroll
        for (int g = 0; g < 4; ++g) {
            int n = n0g + g;
            begv[g] = (n < nl) ? nodeOff[n] : 0;
            cntv[g] = (n < nl) ? nodeCnt[n] : 0;
        }
        int m = cntv[0];
        m = (cntv[1] > m) ? cntv[1] : m;
        m = (cntv[2] > m) ? cntv[2] : m;
        m = (cntv[3] > m) ? cntv[3] : m;
        float A0[4] = {0.f, 0.f, 0.f, 0.f};
        float A1[4] = {0.f, 0.f, 0.f, 0.f};
        for (int j = 0; j + 4 <= m; j += 4) {
            unsigned u[4][4];
            if (act) {
#pragma unroll
                for (int g = 0; g < 4; ++g) {
                    if (j + 4 <= cntv[g]) {
#pragma unroll
                        for (int q = 0; q < 4; ++q)
                            u[g][q] = featbf[(size_t)srcLDS[begv[g] + j + q] * 48 + lane];
                    }
                }
#pragma unroll
                for (int g = 0; g < 4; ++g) {
                    if (j + 4 <= cntv[g]) {
#pragma unroll
                        for (int q = 0; q < 4; ++q) {
                            A0[g] += __uint_as_float(u[g][q] << 16);
                            A1[g] += __uint_as_float(u[g][q] & 0xffff0000u);
                        }
                    }
                }
            }
        }
        // tails: one pair + one single per node (cnt & 3 remaining)
#pragma unroll
        for (int g = 0; g < 4; ++g) {
            int jt = cntv[g] & ~3;
            if (act && jt + 2 <= cntv[g]) {
                unsigned u0 = featbf[(size_t)srcLDS[begv[g] + jt] * 48 + lane];
                unsigned u1 = featbf[(size_t)srcLDS[begv[g] + jt + 1] * 48 + lane];
                A0[g] += __uint_as_float(u0 << 16) + __uint_as_float(u1 << 16);
                A1[g] += __uint_as_float(u0 & 0xffff0000u)
                       + __uint_as_float(u1 & 0xffff0000u);
                jt += 2;
            }
            if (act && jt < cntv[g]) {
                unsigned u0 = featbf[(size_t)srcLDS[begv[g] + jt] * 48 + lane];
                A0[g] += __uint_as_float(u0 << 16);
                A1[g] += __uint_as_float(u0 & 0xffff0000u);
            }
        }
#pragma unroll
        for (int g = 0; g < 4; ++g) {
            int n = n0g + g;
            if (act && n < nl) {
                float inv = 1.0f / fmaxf((float)cntv[g], 1.0f);
                nbr32[(size_t)(n0 + n) * 48 + lane] =
                    (unsigned)f2bf(A0[g] * inv) | ((unsigned)f2bf(A1[g] * inv) << 16);
            }
        }
    }
}

// ---------------------------------------------------------------------------
// mlp3: 8 waves / 512 threads, BM=64 (byte-identical to round 12)
// ---------------------------------------------------------------------------
__global__ __launch_bounds__(512, 4) void mlp3(
    const unsigned int* __restrict__ featbf, const unsigned int* __restrict__ nbr32,
    const unsigned short* __restrict__ W1s, const float* __restrict__ b1,
    const unsigned short* __restrict__ W2s, const float* __restrict__ b2,
    const unsigned short* __restrict__ W3s, const float* __restrict__ b3,
    float* __restrict__ out)
{
    __shared__ __align__(16) char bufA[BM * 512];
    __shared__ __align__(16) char bufB[BM * 512];

    const int t = threadIdx.x;
    const int lane = t & 63;
    const int w = t >> 6;                 // 0..7
    const int row0 = blockIdx.x * BM;
    const int n16 = lane & 15;
    const int kg = lane >> 4;

    for (int i = t; i < BM * 24; i += 512) {
        int row = i / 24, c = i % 24;
        int half = (c >= 12) ? 1 : 0;
        int cg = c - half * 12;
        int grow = row0 + row;
        int lds_byte = (row * 384 + half * 192 + cg * 16) ^ ((row & 7) << 4);
        uint4 v = make_uint4(0u, 0u, 0u, 0u);
        if (grow < N_NODES) {
            const unsigned int* s = half ? nbr32 : featbf;
            v = *reinterpret_cast<const uint4*>(s + (size_t)grow * 48 + cg * 4);
        }
        *reinterpret_cast<uint4*>(bufA + lds_byte) = v;
    }
    __syncthreads();

    // ---- layer 1 ----
    {
        f32x4 acc[4][2];
#pragma unroll
        for (int tt = 0; tt < 2; ++tt) {
            float bb = b1[(w * 2 + tt) * 16 + n16];
#pragma unroll
            for (int mt = 0; mt < 4; ++mt) {
                acc[mt][tt][0] = bb; acc[mt][tt][1] = bb;
                acc[mt][tt][2] = bb; acc[mt][tt][3] = bb;
            }
        }
#pragma unroll
        for (int s = 0; s < 6; ++s) {
            bf16x8 a[4], b[2];
#pragma unroll
            for (int mt = 0; mt < 4; ++mt) {
                int m = mt * 16 + n16;
                int byte_ = (m * 384 + s * 64 + kg * 16) ^ ((m & 7) << 4);
                a[mt] = *reinterpret_cast<const bf16x8*>(bufA + byte_);
            }
#pragma unroll
            for (int tt = 0; tt < 2; ++tt)
                b[tt] = *reinterpret_cast<const bf16x8*>(
                    W1s + ((size_t)((w * 2 + tt) * 6 + s) * 64 + lane) * 8);
#pragma unroll
            for (int mt = 0; mt < 4; ++mt)
#pragma unroll
                for (int tt = 0; tt < 2; ++tt)
                    acc[mt][tt] = __builtin_amdgcn_mfma_f32_16x16x32_bf16(
                        a[mt], b[tt], acc[mt][tt], 0, 0, 0);
        }
#pragma unroll
        for (int mt = 0; mt < 4; ++mt)
#pragma unroll
            for (int tt = 0; tt < 2; ++tt) {
                int col = (w * 2 + tt) * 16 + n16;
#pragma unroll
                for (int r = 0; r < 4; ++r) {
                    int row = mt * 16 + kg * 4 + r;
                    int byte_ = (row * 512 + col * 2) ^ ((row & 7) << 4);
                    *reinterpret_cast<unsigned short*>(bufB + byte_) =
                        f2bf(fmaxf(acc[mt][tt][r], 0.f));
                }
            }
    }
    __syncthreads();

    // ---- layer 2 ----
    {
        f32x4 acc[4][2];
#pragma unroll
        for (int tt = 0; tt < 2; ++tt) {
            float bb = b2[(w * 2 + tt) * 16 + n16];
#pragma unroll
            for (int mt = 0; mt < 4; ++mt) {
                acc[mt][tt][0] = bb; acc[mt][tt][1] = bb;
                acc[mt][tt][2] = bb; acc[mt][tt][3] = bb;
            }
        }
#pragma unroll
        for (int s = 0; s < 8; ++s) {
            bf16x8 a[4], b[2];
#pragma unroll
            for (int mt = 0; mt < 4; ++mt) {
                int m = mt * 16 + n16;
                int byte_ = (m * 512 + s * 64 + kg * 16) ^ ((m & 7) << 4);
                a[mt] = *reinterpret_cast<const bf16x8*>(bufB + byte_);
            }
#pragma unroll
            for (int tt = 0; tt < 2; ++tt)
                b[tt] = *reinterpret_cast<const bf16x8*>(
                    W2s + ((size_t)((w * 2 + tt) * 8 + s) * 64 + lane) * 8);
#pragma unroll
            for (int mt = 0; mt < 4; ++mt)
#pragma unroll
                for (int tt = 0; tt < 2; ++tt)
                    acc[mt][tt] = __builtin_amdgcn_mfma_f32_16x16x32_bf16(
                        a[mt], b[tt], acc[mt][tt], 0, 0, 0);
        }
#pragma unroll
        for (int mt = 0; mt < 4; ++mt)
#pragma unroll
            for (int tt = 0; tt < 2; ++tt) {
                int col = (w * 2 + tt) * 16 + n16;
#pragma unroll
                for (int r = 0; r < 4; ++r) {
                    int row = mt * 16 + kg * 4 + r;
                    int byte_ = (row * 512 + col * 2) ^ ((row & 7) << 4);
                    *reinterpret_cast<unsigned short*>(bufA + byte_) =
                        f2bf(fmaxf(acc[mt][tt][r], 0.f));
                }
            }
    }
    __syncthreads();

    // ---- layer 3 ----
    {
        const int mt3 = w & 3;                 // row tile
        const int tb  = (w >> 2) ? 2 : 0;      // n-tile base
        const int nt3 = (w >> 2) ? 1 : 2;      // n-tiles this wave owns
        f32x4 acc3[2];
#pragma unroll
        for (int tt = 0; tt < 2; ++tt) {
            int col = (tb + tt) * 16 + n16;
            float bb = (tt < nt3 && col < OUTF) ? b3[col] : 0.f;
            acc3[tt][0] = bb; acc3[tt][1] = bb; acc3[tt][2] = bb; acc3[tt][3] = bb;
        }
#pragma unroll
        for (int s = 0; s < 8; ++s) {
            int m = mt3 * 16 + n16;
            int byte_ = (m * 512 + s * 64 + kg * 16) ^ ((m & 7) << 4);
            bf16x8 a = *reinterpret_cast<const bf16x8*>(bufA + byte_);
#pragma unroll
            for (int tt = 0; tt < 2; ++tt) {
                if (tt < nt3) {
                    bf16x8 b = *reinterpret_cast<const bf16x8*>(
                        W3s + ((size_t)((tb + tt) * 8 + s) * 64 + lane) * 8);
                    acc3[tt] = __builtin_amdgcn_mfma_f32_16x16x32_bf16(
                        a, b, acc3[tt], 0, 0, 0);
                }
            }
        }
#pragma unroll
        for (int tt = 0; tt < 2; ++tt) {
            int col = (tb + tt) * 16 + n16;
            if (tt < nt3 && col < OUTF) {
#pragma unroll
                for (int r = 0; r < 4; ++r) {
                    int row = row0 + mt3 * 16 + kg * 4 + r;
                    if (row < N_NODES)
                        out[(size_t)row * OUTF + col] = acc3[tt][r];
                }
            }
        }
    }
}

extern "C" void kernel_launch(void* const* d_in, const int* in_sizes, int n_in,
                              void* d_out, int out_size, void* d_ws, size_t ws_size,
                              hipStream_t stream)
{
    const float* feat = (const float*)d_in[0];
    const int*   src  = (const int*)d_in[1];
    const int*   dst  = (const int*)d_in[2];
    const float* W1   = (const float*)d_in[3];
    const float* b1   = (const float*)d_in[4];
    const float* W2   = (const float*)d_in[5];
    const float* b2   = (const float*)d_in[6];
    const float* W3   = (const float*)d_in[7];
    const float* b3   = (const float*)d_in[8];
    float* out = (float*)d_out;

    // ws layout: cellCnt(NPART*NBE ints = 0.8MB) | packed2 (NPART*NBE*CS u32 =
    //   25.6MB) | featbf (2.4M u32) | nbr32 (2.4M u32) | weights (0.25MB)
    int* cellCnt = (int*)d_ws;
    unsigned int* packed2 = (unsigned int*)(cellCnt + (size_t)NPART * NBE);
    unsigned int* featbf = packed2 + (size_t)NPART * NBE * CS;
    unsigned int* nbr32  = featbf + (size_t)N_NODES * 48;
    unsigned short* W1s  = (unsigned short*)(nbr32 + (size_t)N_NODES * 48);
    unsigned short* W2s  = W1s + 96 * 512;
    unsigned short* W3s  = W2s + 128 * 512;
    // total ~= 0.8 + 25.6 + 9.6 + 9.6 + 0.25 MB ~= 46 MB (ws is 256 MB)

    k1_prep_bin<<<FEAT_BLKS + WSHUF_BLKS + NBE, 256, 0, stream>>>(
        feat, W1, W2, W3, src, dst,
        (uint4*)featbf, W1s, W2s, W3s, packed2, cellCnt);

    part_agg<<<NPART, 1024, 0, stream>>>(packed2, cellCnt, featbf, nbr32);

    mlp3<<<(N_NODES + BM - 1) / BM, 512, 0, stream>>>(
        featbf, nbr32, W1s, b1, W2s, b2, W3s, b3, out);
}

// Round 14
// 78.478 us; speedup vs baseline: 1.0356x; 1.0356x over previous
//
#include <hip/hip_runtime.h>

#define N_NODES 50000
#define N_EDGES 800000
#define DF      96
#define HID     256
#define OUTF    40
#define BM      64
#define NPART   512
#define CS      32     // cell capacity (mean 4; 128B-aligned; overflow ~1e-15)
#define PCAP2   2048   // per-partition LDS sorted capacity (mean ~1563)

#define EPB     2048                                // edges per bin block
#define NBE     ((N_EDGES + EPB - 1) / EPB)         // 391 bin blocks

#define FEAT_THREADS (N_NODES * DF / 8)             // 600000
#define FEAT_BLKS ((FEAT_THREADS + 255) / 256)      // 2344
#define WSHUF_ELEMS ((96 + 128 + 24) * 512)         // 126976
#define WSHUF_BLKS (WSHUF_ELEMS / 256)              // 496

typedef __attribute__((ext_vector_type(8))) short bf16x8;
typedef __attribute__((ext_vector_type(4))) float f32x4;

static __device__ __forceinline__ unsigned short f2bf(float f) {
    unsigned int u = __float_as_uint(f);
    u += 0x7fffu + ((u >> 16) & 1u);
    return (unsigned short)(u >> 16);
}
static __device__ __forceinline__ int part_of(int d) {
    return (int)(((long long)d * NPART) / N_NODES);
}
static __device__ __forceinline__ int part_n0(int p) {
    return (int)(((long long)p * N_NODES + NPART - 1) / NPART);
}

// ---------------------------------------------------------------------------
// K1: feat f32->bf16 | weight pre-shuffle | cell-based edge binning (NPART=512)
// ---------------------------------------------------------------------------
__global__ __launch_bounds__(256) void k1_prep_bin(
    const float* __restrict__ feat, const float* __restrict__ W1,
    const float* __restrict__ W2, const float* __restrict__ W3,
    const int* __restrict__ src, const int* __restrict__ dst,
    uint4* __restrict__ featbf, unsigned short* __restrict__ W1s,
    unsigned short* __restrict__ W2s, unsigned short* __restrict__ W3s,
    unsigned int* __restrict__ packed2, int* __restrict__ cellCnt)
{
    const int bid = blockIdx.x, t = threadIdx.x;
    if (bid < FEAT_BLKS) {
        int i = bid * 256 + t;                     // 8 floats per thread
        if (i < FEAT_THREADS) {
            const float4* p = reinterpret_cast<const float4*>(feat) + (size_t)i * 2;
            float4 v0 = p[0], v1 = p[1];
            uint4 pk;
            pk.x = (unsigned)f2bf(v0.x) | ((unsigned)f2bf(v0.y) << 16);
            pk.y = (unsigned)f2bf(v0.z) | ((unsigned)f2bf(v0.w) << 16);
            pk.z = (unsigned)f2bf(v1.x) | ((unsigned)f2bf(v1.y) << 16);
            pk.w = (unsigned)f2bf(v1.z) | ((unsigned)f2bf(v1.w) << 16);
            featbf[i] = pk;
        }
        return;
    }
    if (bid < FEAT_BLKS + WSHUF_BLKS) {
        int i = (bid - FEAT_BLKS) * 256 + t;       // < WSHUF_ELEMS exactly
        int j  = i & 7;
        int l  = (i >> 3) & 63;
        int fi = i >> 9;
        int kg = l >> 4, n16 = l & 15;
        if (fi < 96) {
            int tt = fi / 6, s = fi % 6;
            int k = s * 32 + kg * 8 + j, n = tt * 16 + n16;
            W1s[i] = f2bf(W1[(size_t)k * HID + n]);
        } else if (fi < 96 + 128) {
            int f2 = fi - 96;
            int tt = f2 / 8, s = f2 % 8;
            int k = s * 32 + kg * 8 + j, n = tt * 16 + n16;
            W2s[i - 96 * 512] = f2bf(W2[(size_t)k * HID + n]);
        } else {
            int f3 = fi - 224;
            int tt = f3 / 8, s = f3 % 8;
            int k = s * 32 + kg * 8 + j, n = tt * 16 + n16;
            W3s[i - 224 * 512] = (n < OUTF) ? f2bf(W3[(size_t)k * OUTF + n])
                                            : (unsigned short)0;
        }
        return;
    }
    // ---- edge binning ----
    {
        __shared__ int cur[NPART];
        const int bid2 = bid - FEAT_BLKS - WSHUF_BLKS;   // < NBE
        cur[t] = 0;
        cur[t + 256] = 0;
        __syncthreads();
        int pv[8], pos[8];
        unsigned pkv[8];
        bool valid[8];
#pragma unroll
        for (int k = 0; k < 8; ++k) {
            int e = bid2 * EPB + k * 256 + t;
            valid[k] = (e < N_EDGES);
            pv[k] = 0; pkv[k] = 0; pos[k] = CS;
            if (valid[k]) {
                int d = dst[e], s = src[e];
                int p = part_of(d);
                pv[k] = p;
                pkv[k] = ((unsigned)(d - part_n0(p)) << 16) | (unsigned)s;
                pos[k] = atomicAdd(&cur[p], 1);
            }
        }
        __syncthreads();
#pragma unroll
        for (int q = 0; q < 2; ++q) {
            int pp = q * 256 + t;
            cellCnt[(size_t)pp * NBE + bid2] = (cur[pp] < CS) ? cur[pp] : CS;
        }
#pragma unroll
        for (int k = 0; k < 8; ++k) {
            if (valid[k] && pos[k] < CS)
                packed2[((size_t)pv[k] * NBE + bid2) * CS + pos[k]] = pkv[k];
        }
    }
}

// ---------------------------------------------------------------------------
// part_agg: per-partition in-LDS counting sort + neighbor-mean aggregation.
// 512 blocks x 1024 threads (16 waves) -> 32 waves/CU, ~6 serial nodes/wave,
// LDS-resident gather indices, depth-8 gather. Empirically optimal
// (rounds 8, 11, 13 probed lower occupancy / longer chains / wider MLP:
// all neutral-or-worse — the gather sits at its L3 service floor).
// ---------------------------------------------------------------------------
__global__ __launch_bounds__(1024, 4) void part_agg(
    const unsigned int* __restrict__ packed2, const int* __restrict__ cellCnt,
    const unsigned int* __restrict__ featbf, unsigned int* __restrict__ nbr32)
{
    __shared__ int hist[128];
    __shared__ int scanex[128];
    __shared__ int cur[128];
    __shared__ int nodeOff[128];
    __shared__ int nodeCnt[128];
    __shared__ unsigned short srcLDS[PCAP2];
    const int p = blockIdx.x, t = threadIdx.x;
    const int n0 = part_n0(p);
    const int nl = part_n0(p + 1) - n0;              // <= 98
    const unsigned int* cells = packed2 + (size_t)p * NBE * CS;
    const int* ccnt = cellCnt + (size_t)p * NBE;

    if (t < 128) hist[t] = 0;
    __syncthreads();
    // pass 1: histogram of dst_local over cell prefixes
    for (int c = t; c < NBE; c += 1024) {
        int cnt = ccnt[c];
        const unsigned int* cp = cells + (size_t)c * CS;
        for (int i = 0; i < cnt; ++i)
            atomicAdd(&hist[cp[i] >> 16], 1);
    }
    __syncthreads();
    int v = 0;
    if (t < 128) { v = hist[t]; scanex[t] = v; }
    __syncthreads();
    for (int off = 1; off < 128; off <<= 1) {
        int x = 0;
        if (t < 128 && t >= off) x = scanex[t - off];
        __syncthreads();
        if (t < 128) scanex[t] += x;
        __syncthreads();
    }
    if (t < 128) {
        int ex = scanex[t] - v;
        cur[t] = ex;
        nodeOff[t] = ex;
        nodeCnt[t] = v;
    }
    __syncthreads();
    // pass 2: rank into LDS
    for (int c = t; c < NBE; c += 1024) {
        int cnt = ccnt[c];
        const unsigned int* cp = cells + (size_t)c * CS;
        for (int i = 0; i < cnt; ++i) {
            unsigned pk = cp[i];
            int r = atomicAdd(&cur[pk >> 16], 1);
            if (r < PCAP2) srcLDS[r] = (unsigned short)(pk & 0xffffu);
        }
    }
    __syncthreads();
    // gather: wave per node, 8/2/1-unrolled, indices from LDS
    const int wv = t >> 6, lane = t & 63;
    const bool act = (lane < 48);
    for (int n = wv; n < nl; n += 16) {
        int beg = nodeOff[n];
        int cnt = nodeCnt[n];
        float a0 = 0.f, a1 = 0.f;
        int j = 0;
        for (; j + 8 <= cnt; j += 8) {
            unsigned u[8];
            if (act) {
#pragma unroll
                for (int q = 0; q < 8; ++q)
                    u[q] = featbf[(size_t)srcLDS[beg + j + q] * 48 + lane];
#pragma unroll
                for (int q = 0; q < 8; ++q) {
                    a0 += __uint_as_float(u[q] << 16);
                    a1 += __uint_as_float(u[q] & 0xffff0000u);
                }
            }
        }
        for (; j + 2 <= cnt; j += 2) {
            if (act) {
                unsigned u0 = featbf[(size_t)srcLDS[beg + j] * 48 + lane];
                unsigned u1 = featbf[(size_t)srcLDS[beg + j + 1] * 48 + lane];
                a0 += __uint_as_float(u0 << 16) + __uint_as_float(u1 << 16);
                a1 += __uint_as_float(u0 & 0xffff0000u)
                    + __uint_as_float(u1 & 0xffff0000u);
            }
        }
        if (j < cnt && act) {
            unsigned u0 = featbf[(size_t)srcLDS[beg + j] * 48 + lane];
            a0 += __uint_as_float(u0 << 16);
            a1 += __uint_as_float(u0 & 0xffff0000u);
        }
        float inv = 1.0f / fmaxf((float)cnt, 1.0f);
        if (act)
            nbr32[(size_t)(n0 + n) * 48 + lane] =
                (unsigned)f2bf(a0 * inv) | ((unsigned)f2bf(a1 * inv) << 16);
    }
}

// ---------------------------------------------------------------------------
// mlp3: 8 waves / 512 threads, BM=64
// ---------------------------------------------------------------------------
__global__ __launch_bounds__(512, 4) void mlp3(
    const unsigned int* __restrict__ featbf, const unsigned int* __restrict__ nbr32,
    const unsigned short* __restrict__ W1s, const float* __restrict__ b1,
    const unsigned short* __restrict__ W2s, const float* __restrict__ b2,
    const unsigned short* __restrict__ W3s, const float* __restrict__ b3,
    float* __restrict__ out)
{
    __shared__ __align__(16) char bufA[BM * 512];
    __shared__ __align__(16) char bufB[BM * 512];

    const int t = threadIdx.x;
    const int lane = t & 63;
    const int w = t >> 6;                 // 0..7
    const int row0 = blockIdx.x * BM;
    const int n16 = lane & 15;
    const int kg = lane >> 4;

    for (int i = t; i < BM * 24; i += 512) {
        int row = i / 24, c = i % 24;
        int half = (c >= 12) ? 1 : 0;
        int cg = c - half * 12;
        int grow = row0 + row;
        int lds_byte = (row * 384 + half * 192 + cg * 16) ^ ((row & 7) << 4);
        uint4 v = make_uint4(0u, 0u, 0u, 0u);
        if (grow < N_NODES) {
            const unsigned int* s = half ? nbr32 : featbf;
            v = *reinterpret_cast<const uint4*>(s + (size_t)grow * 48 + cg * 4);
        }
        *reinterpret_cast<uint4*>(bufA + lds_byte) = v;
    }
    __syncthreads();

    // ---- layer 1 ----
    {
        f32x4 acc[4][2];
#pragma unroll
        for (int tt = 0; tt < 2; ++tt) {
            float bb = b1[(w * 2 + tt) * 16 + n16];
#pragma unroll
            for (int mt = 0; mt < 4; ++mt) {
                acc[mt][tt][0] = bb; acc[mt][tt][1] = bb;
                acc[mt][tt][2] = bb; acc[mt][tt][3] = bb;
            }
        }
#pragma unroll
        for (int s = 0; s < 6; ++s) {
            bf16x8 a[4], b[2];
#pragma unroll
            for (int mt = 0; mt < 4; ++mt) {
                int m = mt * 16 + n16;
                int byte_ = (m * 384 + s * 64 + kg * 16) ^ ((m & 7) << 4);
                a[mt] = *reinterpret_cast<const bf16x8*>(bufA + byte_);
            }
#pragma unroll
            for (int tt = 0; tt < 2; ++tt)
                b[tt] = *reinterpret_cast<const bf16x8*>(
                    W1s + ((size_t)((w * 2 + tt) * 6 + s) * 64 + lane) * 8);
#pragma unroll
            for (int mt = 0; mt < 4; ++mt)
#pragma unroll
                for (int tt = 0; tt < 2; ++tt)
                    acc[mt][tt] = __builtin_amdgcn_mfma_f32_16x16x32_bf16(
                        a[mt], b[tt], acc[mt][tt], 0, 0, 0);
        }
#pragma unroll
        for (int mt = 0; mt < 4; ++mt)
#pragma unroll
            for (int tt = 0; tt < 2; ++tt) {
                int col = (w * 2 + tt) * 16 + n16;
#pragma unroll
                for (int r = 0; r < 4; ++r) {
                    int row = mt * 16 + kg * 4 + r;
                    int byte_ = (row * 512 + col * 2) ^ ((row & 7) << 4);
                    *reinterpret_cast<unsigned short*>(bufB + byte_) =
                        f2bf(fmaxf(acc[mt][tt][r], 0.f));
                }
            }
    }
    __syncthreads();

    // ---- layer 2 ----
    {
        f32x4 acc[4][2];
#pragma unroll
        for (int tt = 0; tt < 2; ++tt) {
            float bb = b2[(w * 2 + tt) * 16 + n16];
#pragma unroll
            for (int mt = 0; mt < 4; ++mt) {
                acc[mt][tt][0] = bb; acc[mt][tt][1] = bb;
                acc[mt][tt][2] = bb; acc[mt][tt][3] = bb;
            }
        }
#pragma unroll
        for (int s = 0; s < 8; ++s) {
            bf16x8 a[4], b[2];
#pragma unroll
            for (int mt = 0; mt < 4; ++mt) {
                int m = mt * 16 + n16;
                int byte_ = (m * 512 + s * 64 + kg * 16) ^ ((m & 7) << 4);
                a[mt] = *reinterpret_cast<const bf16x8*>(bufB + byte_);
            }
#pragma unroll
            for (int tt = 0; tt < 2; ++tt)
                b[tt] = *reinterpret_cast<const bf16x8*>(
                    W2s + ((size_t)((w * 2 + tt) * 8 + s) * 64 + lane) * 8);
#pragma unroll
            for (int mt = 0; mt < 4; ++mt)
#pragma unroll
                for (int tt = 0; tt < 2; ++tt)
                    acc[mt][tt] = __builtin_amdgcn_mfma_f32_16x16x32_bf16(
                        a[mt], b[tt], acc[mt][tt], 0, 0, 0);
        }
#pragma unroll
        for (int mt = 0; mt < 4; ++mt)
#pragma unroll
            for (int tt = 0; tt < 2; ++tt) {
                int col = (w * 2 + tt) * 16 + n16;
#pragma unroll
                for (int r = 0; r < 4; ++r) {
                    int row = mt * 16 + kg * 4 + r;
                    int byte_ = (row * 512 + col * 2) ^ ((row & 7) << 4);
                    *reinterpret_cast<unsigned short*>(bufA + byte_) =
                        f2bf(fmaxf(acc[mt][tt][r], 0.f));
                }
            }
    }
    __syncthreads();

    // ---- layer 3 ----
    {
        const int mt3 = w & 3;                 // row tile
        const int tb  = (w >> 2) ? 2 : 0;      // n-tile base
        const int nt3 = (w >> 2) ? 1 : 2;      // n-tiles this wave owns
        f32x4 acc3[2];
#pragma unroll
        for (int tt = 0; tt < 2; ++tt) {
            int col = (tb + tt) * 16 + n16;
            float bb = (tt < nt3 && col < OUTF) ? b3[col] : 0.f;
            acc3[tt][0] = bb; acc3[tt][1] = bb; acc3[tt][2] = bb; acc3[tt][3] = bb;
        }
#pragma unroll
        for (int s = 0; s < 8; ++s) {
            int m = mt3 * 16 + n16;
            int byte_ = (m * 512 + s * 64 + kg * 16) ^ ((m & 7) << 4);
            bf16x8 a = *reinterpret_cast<const bf16x8*>(bufA + byte_);
#pragma unroll
            for (int tt = 0; tt < 2; ++tt) {
                if (tt < nt3) {
                    bf16x8 b = *reinterpret_cast<const bf16x8*>(
                        W3s + ((size_t)((tb + tt) * 8 + s) * 64 + lane) * 8);
                    acc3[tt] = __builtin_amdgcn_mfma_f32_16x16x32_bf16(
                        a, b, acc3[tt], 0, 0, 0);
                }
            }
        }
#pragma unroll
        for (int tt = 0; tt < 2; ++tt) {
            int col = (tb + tt) * 16 + n16;
            if (tt < nt3 && col < OUTF) {
#pragma unroll
                for (int r = 0; r < 4; ++r) {
                    int row = row0 + mt3 * 16 + kg * 4 + r;
                    if (row < N_NODES)
                        out[(size_t)row * OUTF + col] = acc3[tt][r];
                }
            }
        }
    }
}

extern "C" void kernel_launch(void* const* d_in, const int* in_sizes, int n_in,
                              void* d_out, int out_size, void* d_ws, size_t ws_size,
                              hipStream_t stream)
{
    const float* feat = (const float*)d_in[0];
    const int*   src  = (const int*)d_in[1];
    const int*   dst  = (const int*)d_in[2];
    const float* W1   = (const float*)d_in[3];
    const float* b1   = (const float*)d_in[4];
    const float* W2   = (const float*)d_in[5];
    const float* b2   = (const float*)d_in[6];
    const float* W3   = (const float*)d_in[7];
    const float* b3   = (const float*)d_in[8];
    float* out = (float*)d_out;

    // ws layout: cellCnt(NPART*NBE ints = 0.8MB) | packed2 (NPART*NBE*CS u32 =
    //   25.6MB) | featbf (2.4M u32) | nbr32 (2.4M u32) | weights (0.25MB)
    int* cellCnt = (int*)d_ws;
    unsigned int* packed2 = (unsigned int*)(cellCnt + (size_t)NPART * NBE);
    unsigned int* featbf = packed2 + (size_t)NPART * NBE * CS;
    unsigned int* nbr32  = featbf + (size_t)N_NODES * 48;
    unsigned short* W1s  = (unsigned short*)(nbr32 + (size_t)N_NODES * 48);
    unsigned short* W2s  = W1s + 96 * 512;
    unsigned short* W3s  = W2s + 128 * 512;
    // total ~= 0.8 + 25.6 + 9.6 + 9.6 + 0.25 MB ~= 46 MB (ws is 256 MB)

    k1_prep_bin<<<FEAT_BLKS + WSHUF_BLKS + NBE, 256, 0, stream>>>(
        feat, W1, W2, W3, src, dst,
        (uint4*)featbf, W1s, W2s, W3s, packed2, cellCnt);

    part_agg<<<NPART, 1024, 0, stream>>>(packed2, cellCnt, featbf, nbr32);

    mlp3<<<(N_NODES + BM - 1) / BM, 512, 0, stream>>>(
        featbf, nbr32, W1s, b1, W2s, b2, W3s, b3, out);
}